// Round 1
// baseline (517.187 us; speedup 1.0000x reference)
//
#include <hip/hip_runtime.h>
#include <math.h>

#define N_SEQ 1024
#define LL 64
#define DH 256
#define DX 128
#define MQ 8192
#define GG 4096
#define NTYP 64
#define NMEM 262144

// ---------------- scatter: z[grp[i]] += tok_emb[mem[i]] ----------------
__global__ __launch_bounds__(256) void k_scatter(const int* __restrict__ mem,
                                                 const int* __restrict__ grp,
                                                 const float* __restrict__ tok_emb,
                                                 float* __restrict__ z) {
    int wave = (blockIdx.x * blockDim.x + threadIdx.x) >> 6;
    int lane = threadIdx.x & 63;
    if (wave >= NMEM) return;
    int t = mem[wave];
    int g = grp[wave];
    const float2* s = (const float2*)(tok_emb + (size_t)t * DX);
    float2 v = s[lane];
    float* d = z + (size_t)g * DX + lane * 2;
    atomicAdd(d, v.x);
    atomicAdd(d + 1, v.y);
}

// ---------------- qp = cat(h[idx,src], h[idx,dst]) @ Wq + bq; also store q --
#define TMQ 16
__global__ __launch_bounds__(256) void k_qp(const float* __restrict__ h_grp,
                                            const int* __restrict__ idx,
                                            const int* __restrict__ srcv,
                                            const int* __restrict__ dstv,
                                            const float* __restrict__ Wq,
                                            const float* __restrict__ bq,
                                            float* __restrict__ q_out,
                                            float* __restrict__ qp_out) {
    __shared__ __align__(16) float qs[TMQ][512];
    int m0 = blockIdx.x * TMQ;
    int tid = threadIdx.x;
    for (int mm = 0; mm < TMQ; ++mm) {
        int m = m0 + mm;
        int n = idx[m], s = srcv[m], d = dstv[m];
        float v1 = h_grp[((size_t)n * LL + s) * DH + tid];
        float v2 = h_grp[((size_t)n * LL + d) * DH + tid];
        qs[mm][tid] = v1;
        qs[mm][256 + tid] = v2;
        q_out[(size_t)m * 512 + tid] = v1;
        q_out[(size_t)m * 512 + 256 + tid] = v2;
    }
    __syncthreads();
    float acc[TMQ];
    float b = bq[tid];
#pragma unroll
    for (int mm = 0; mm < TMQ; ++mm) acc[mm] = b;
    const float4* qs4 = nullptr;
    for (int d4 = 0; d4 < 128; ++d4) {
        float w0 = Wq[(size_t)(d4 * 4 + 0) * 256 + tid];
        float w1 = Wq[(size_t)(d4 * 4 + 1) * 256 + tid];
        float w2 = Wq[(size_t)(d4 * 4 + 2) * 256 + tid];
        float w3 = Wq[(size_t)(d4 * 4 + 3) * 256 + tid];
#pragma unroll
        for (int mm = 0; mm < TMQ; ++mm) {
            float4 qv = ((const float4*)qs[mm])[d4];
            acc[mm] += qv.x * w0 + qv.y * w1 + qv.z * w2 + qv.w * w3;
        }
    }
    for (int mm = 0; mm < TMQ; ++mm)
        qp_out[(size_t)(m0 + mm) * 256 + tid] = acc[mm];
    (void)qs4;
}

// ---------------- transpose Wk (256x256) -> WkT[e*256+d] = Wk[d*256+e] ------
__global__ void k_transpose(const float* __restrict__ Wk, float* __restrict__ WkT) {
    __shared__ float tile[32][33];
    int tx = threadIdx.x, ty = threadIdx.y;
    int bx = blockIdx.x, by = blockIdx.y;
    tile[ty][tx] = Wk[(size_t)(by * 32 + ty) * 256 + bx * 32 + tx];
    __syncthreads();
    WkT[(size_t)(bx * 32 + ty) * 256 + by * 32 + tx] = tile[tx][ty];
}

// ---------------- qk = qp @ WkT^T (i.e. qk[m,d]=sum_e Wk[d,e] qp[m,e]); qb=bk.qp
__global__ __launch_bounds__(256) void k_qk(const float* __restrict__ qp,
                                            const float* __restrict__ WkT,
                                            const float* __restrict__ bk,
                                            float* __restrict__ qk,
                                            float* __restrict__ qb) {
    __shared__ __align__(16) float ps[TMQ][256];
    int m0 = blockIdx.x * TMQ;
    int tid = threadIdx.x;
    for (int mm = 0; mm < TMQ; ++mm)
        ps[mm][tid] = qp[(size_t)(m0 + mm) * 256 + tid];
    __syncthreads();
    float acc[TMQ];
#pragma unroll
    for (int mm = 0; mm < TMQ; ++mm) acc[mm] = 0.f;
    for (int e4 = 0; e4 < 64; ++e4) {
        float w0 = WkT[(size_t)(e4 * 4 + 0) * 256 + tid];
        float w1 = WkT[(size_t)(e4 * 4 + 1) * 256 + tid];
        float w2 = WkT[(size_t)(e4 * 4 + 2) * 256 + tid];
        float w3 = WkT[(size_t)(e4 * 4 + 3) * 256 + tid];
#pragma unroll
        for (int mm = 0; mm < TMQ; ++mm) {
            float4 pv = ((const float4*)ps[mm])[e4];
            acc[mm] += pv.x * w0 + pv.y * w1 + pv.z * w2 + pv.w * w3;
        }
    }
    for (int mm = 0; mm < TMQ; ++mm)
        qk[(size_t)(m0 + mm) * 256 + tid] = acc[mm];
    if (tid < TMQ) {
        float s = 0.f;
        for (int e = 0; e < 256; ++e) s += bk[e] * ps[tid][e];
        qb[m0 + tid] = s;
    }
}

// ---------------- attention: scores -> softmax -> ctx ----------------------
__global__ __launch_bounds__(256) void k_attn(const float* __restrict__ h_grp,
                                              const int* __restrict__ idx,
                                              const int* __restrict__ pos2grp,
                                              const int* __restrict__ msk,
                                              const float* __restrict__ z,
                                              const float* __restrict__ qk,
                                              const float* __restrict__ qb,
                                              float* __restrict__ ctx) {
    int m = blockIdx.x;
    int n = idx[m];
    __shared__ __align__(16) float qks[256];
    __shared__ float attn_s[LL];
    __shared__ int grp_s[LL];
    int tid = threadIdx.x;
    int lane = tid & 63;
    int w = tid >> 6;
    qks[tid] = qk[(size_t)m * 256 + tid];
    if (tid < LL) grp_s[tid] = pos2grp[n * LL + tid];
    __syncthreads();
    float qbv = qb[m];
    const float4* qk4 = (const float4*)qks;
    float4 qv = qk4[lane];
    for (int i = 0; i < 16; ++i) {
        int l = w * 16 + i;
        const float4* h4 = (const float4*)(h_grp + ((size_t)n * LL + l) * DH);
        float4 hv = h4[lane];
        float p = hv.x * qv.x + hv.y * qv.y + hv.z * qv.z + hv.w * qv.w;
        for (int off = 32; off; off >>= 1) p += __shfl_xor(p, off);
        if (lane == 0) {
            float s = (p + qbv) * (1.0f / 16.0f);
            attn_s[l] = msk[n * LL + l] ? s : -INFINITY;
        }
    }
    __syncthreads();
    if (tid < LL) {
        float s = attn_s[tid];
        float mx = s;
        for (int off = 32; off; off >>= 1) mx = fmaxf(mx, __shfl_xor(mx, off));
        float p = __expf(s - mx);
        float sum = p;
        for (int off = 32; off; off >>= 1) sum += __shfl_xor(sum, off);
        attn_s[tid] = p / sum;
    }
    __syncthreads();
    if (tid < DX) {
        int v = tid;
        float acc = 0.f;
        for (int l = 0; l < LL; ++l)
            acc += attn_s[l] * z[(size_t)grp_s[l] * DX + v];
        ctx[(size_t)m * DX + v] = acc;
    }
}

// ---------------- logit = cat(q, ctx) @ Wrel + brel ------------------------
#define TML 4
__global__ __launch_bounds__(256) void k_logit(const float* __restrict__ q,
                                               const float* __restrict__ ctx,
                                               const float* __restrict__ Wrel,
                                               const float* __restrict__ brel,
                                               float* __restrict__ out) {
    __shared__ __align__(16) float ins[TML][640];
    int m0 = blockIdx.x * TML;
    int tid = threadIdx.x;
    for (int j = tid; j < TML * 640; j += 256) {
        int mmj = j / 640, jj = j % 640;
        int mj = m0 + mmj;
        ins[mmj][jj] = (jj < 512) ? q[(size_t)mj * 512 + jj]
                                  : ctx[(size_t)mj * 128 + (jj - 512)];
    }
    __syncthreads();
    int mm = tid >> 6;
    int t = tid & 63;
    float acc = brel[t];
    const float4* in4 = (const float4*)ins[mm];
    for (int j4 = 0; j4 < 160; ++j4) {
        float4 iv = in4[j4];
        acc += iv.x * Wrel[(size_t)(j4 * 4 + 0) * 64 + t];
        acc += iv.y * Wrel[(size_t)(j4 * 4 + 1) * 64 + t];
        acc += iv.z * Wrel[(size_t)(j4 * 4 + 2) * 64 + t];
        acc += iv.w * Wrel[(size_t)(j4 * 4 + 3) * 64 + t];
    }
    out[(size_t)(m0 + mm) * 64 + t] = acc;
}

extern "C" void kernel_launch(void* const* d_in, const int* in_sizes, int n_in,
                              void* d_out, int out_size, void* d_ws, size_t ws_size,
                              hipStream_t stream) {
    const int*   mem     = (const int*)d_in[0];
    const int*   grp     = (const int*)d_in[1];
    const int*   pos2grp = (const int*)d_in[2];
    const float* h_grp   = (const float*)d_in[3];
    const int*   msk     = (const int*)d_in[4];
    const int*   idx     = (const int*)d_in[5];
    const int*   srcv    = (const int*)d_in[6];
    const int*   dstv    = (const int*)d_in[7];
    // d_in[8] = typ (unused by the reference)
    const float* tok_emb = (const float*)d_in[9];
    const float* Wq      = (const float*)d_in[10];
    const float* bq      = (const float*)d_in[11];
    const float* Wk      = (const float*)d_in[12];
    const float* bk      = (const float*)d_in[13];
    const float* Wrel    = (const float*)d_in[14];
    const float* brel    = (const float*)d_in[15];
    float* out = (float*)d_out;

    float* ws = (float*)d_ws;
    size_t off = 0;
    float* z    = ws + off; off += (size_t)GG * DX;       // 524288
    float* q    = ws + off; off += (size_t)MQ * 512;      // 4194304
    float* qp   = ws + off; off += (size_t)MQ * 256;      // 2097152
    float* qk   = ws + off; off += (size_t)MQ * 256;      // 2097152
    float* qb   = ws + off; off += (size_t)MQ;            // 8192
    float* ctx  = ws + off; off += (size_t)MQ * DX;       // 1048576
    float* WkT  = ws + off; off += (size_t)DH * DH;       // 65536

    hipMemsetAsync(z, 0, (size_t)GG * DX * sizeof(float), stream);

    k_scatter<<<NMEM / 4, 256, 0, stream>>>(mem, grp, tok_emb, z);

    k_qp<<<MQ / TMQ, 256, 0, stream>>>(h_grp, idx, srcv, dstv, Wq, bq, q, qp);

    dim3 tb(32, 32);
    dim3 tg(8, 8);
    k_transpose<<<tg, tb, 0, stream>>>(Wk, WkT);

    k_qk<<<MQ / TMQ, 256, 0, stream>>>(qp, WkT, bk, qk, qb);

    k_attn<<<MQ, 256, 0, stream>>>(h_grp, idx, pos2grp, msk, z, qk, qb, ctx);

    k_logit<<<MQ / TML, 256, 0, stream>>>(q, ctx, Wrel, brel, out);
}

// Round 2
// 356.551 us; speedup vs baseline: 1.4505x; 1.4505x over previous
//
#include <hip/hip_runtime.h>
#include <math.h>

#define N_SEQ 1024
#define LL 64
#define DH 256
#define DX 128
#define MQ 8192
#define GG 4096
#define NTYP 64
#define NMEM 262144

// ---------------- counting-sort based segment sum ---------------------------
__global__ __launch_bounds__(256) void k_hist(const int* __restrict__ grp,
                                              int* __restrict__ cnt) {
    int i = blockIdx.x * 256 + threadIdx.x;
    if (i < NMEM) atomicAdd(&cnt[grp[i]], 1);
}

// single block, 1024 threads, 4 counts per thread -> exclusive scan
__global__ __launch_bounds__(1024) void k_scan(const int* __restrict__ cnt,
                                               int* __restrict__ ofs,
                                               int* __restrict__ cur) {
    __shared__ int wsum[16];
    int tid = threadIdx.x;
    int4 c = ((const int4*)cnt)[tid];
    int local = c.x + c.y + c.z + c.w;
    int lane = tid & 63, w = tid >> 6;
    int v = local;
    for (int off = 1; off < 64; off <<= 1) {
        int t = __shfl_up(v, off);
        if (lane >= off) v += t;
    }
    if (lane == 63) wsum[w] = v;
    __syncthreads();
    if (tid < 16) {
        int s = wsum[tid];
        for (int off = 1; off < 16; off <<= 1) {
            int t = __shfl_up(s, off);
            if (tid >= off) s += t;
        }
        wsum[tid] = s;
    }
    __syncthreads();
    int base = (w > 0 ? wsum[w - 1] : 0) + (v - local);
    int4 o;
    o.x = base;
    o.y = base + c.x;
    o.z = o.y + c.y;
    o.w = o.z + c.z;
    ((int4*)ofs)[tid] = o;
    ((int4*)cur)[tid] = o;
}

__global__ __launch_bounds__(256) void k_permute(const int* __restrict__ grp,
                                                 const int* __restrict__ mem,
                                                 int* __restrict__ cur,
                                                 int* __restrict__ tok_sorted) {
    int i = blockIdx.x * 256 + threadIdx.x;
    if (i < NMEM) {
        int g = grp[i];
        int pos = atomicAdd(&cur[g], 1);
        tok_sorted[pos] = mem[i];
    }
}

// one block (128 threads) per group: z[g] = sum of tok_emb rows
__global__ __launch_bounds__(128) void k_zsum(const int* __restrict__ ofs,
                                              const int* __restrict__ cnt,
                                              const int* __restrict__ tok_sorted,
                                              const float* __restrict__ tok_emb,
                                              float* __restrict__ z) {
    __shared__ int idxs[128];
    int g = blockIdx.x;
    int tid = threadIdx.x;
    int start = ofs[g], n = cnt[g];
    float acc = 0.f;
    for (int j0 = 0; j0 < n; j0 += 128) {
        __syncthreads();
        int rem = n - j0;
        if (tid < rem) idxs[tid] = tok_sorted[start + j0 + tid];
        __syncthreads();
        int kmax = rem < 128 ? rem : 128;
        for (int k = 0; k < kmax; ++k)
            acc += tok_emb[(size_t)idxs[k] * DX + tid];
    }
    z[(size_t)g * DX + tid] = acc;
}

// ---------------- qp = cat(h[idx,src], h[idx,dst]) @ Wq + bq; also store q --
#define TMQ 16
__global__ __launch_bounds__(256) void k_qp(const float* __restrict__ h_grp,
                                            const int* __restrict__ idx,
                                            const int* __restrict__ srcv,
                                            const int* __restrict__ dstv,
                                            const float* __restrict__ Wq,
                                            const float* __restrict__ bq,
                                            float* __restrict__ q_out,
                                            float* __restrict__ qp_out) {
    __shared__ __align__(16) float qs[TMQ][512];
    int m0 = blockIdx.x * TMQ;
    int tid = threadIdx.x;
    for (int mm = 0; mm < TMQ; ++mm) {
        int m = m0 + mm;
        int n = idx[m], s = srcv[m], d = dstv[m];
        float v1 = h_grp[((size_t)n * LL + s) * DH + tid];
        float v2 = h_grp[((size_t)n * LL + d) * DH + tid];
        qs[mm][tid] = v1;
        qs[mm][256 + tid] = v2;
        q_out[(size_t)m * 512 + tid] = v1;
        q_out[(size_t)m * 512 + 256 + tid] = v2;
    }
    __syncthreads();
    float acc[TMQ];
    float b = bq[tid];
#pragma unroll
    for (int mm = 0; mm < TMQ; ++mm) acc[mm] = b;
    for (int d4 = 0; d4 < 128; ++d4) {
        float w0 = Wq[(size_t)(d4 * 4 + 0) * 256 + tid];
        float w1 = Wq[(size_t)(d4 * 4 + 1) * 256 + tid];
        float w2 = Wq[(size_t)(d4 * 4 + 2) * 256 + tid];
        float w3 = Wq[(size_t)(d4 * 4 + 3) * 256 + tid];
#pragma unroll
        for (int mm = 0; mm < TMQ; ++mm) {
            float4 qv = ((const float4*)qs[mm])[d4];
            acc[mm] += qv.x * w0 + qv.y * w1 + qv.z * w2 + qv.w * w3;
        }
    }
    for (int mm = 0; mm < TMQ; ++mm)
        qp_out[(size_t)(m0 + mm) * 256 + tid] = acc[mm];
}

// ---------------- transpose Wk (256x256) -> WkT[e*256+d] = Wk[d*256+e] ------
__global__ void k_transpose(const float* __restrict__ Wk, float* __restrict__ WkT) {
    __shared__ float tile[32][33];
    int tx = threadIdx.x, ty = threadIdx.y;
    int bx = blockIdx.x, by = blockIdx.y;
    tile[ty][tx] = Wk[(size_t)(by * 32 + ty) * 256 + bx * 32 + tx];
    __syncthreads();
    WkT[(size_t)(bx * 32 + ty) * 256 + by * 32 + tx] = tile[tx][ty];
}

// ---------------- qk[m,d]=sum_e Wk[d,e] qp[m,e]; qb=bk.qp -------------------
__global__ __launch_bounds__(256) void k_qk(const float* __restrict__ qp,
                                            const float* __restrict__ WkT,
                                            const float* __restrict__ bk,
                                            float* __restrict__ qk,
                                            float* __restrict__ qb) {
    __shared__ __align__(16) float ps[TMQ][256];
    int m0 = blockIdx.x * TMQ;
    int tid = threadIdx.x;
    for (int mm = 0; mm < TMQ; ++mm)
        ps[mm][tid] = qp[(size_t)(m0 + mm) * 256 + tid];
    __syncthreads();
    float acc[TMQ];
#pragma unroll
    for (int mm = 0; mm < TMQ; ++mm) acc[mm] = 0.f;
    for (int e4 = 0; e4 < 64; ++e4) {
        float w0 = WkT[(size_t)(e4 * 4 + 0) * 256 + tid];
        float w1 = WkT[(size_t)(e4 * 4 + 1) * 256 + tid];
        float w2 = WkT[(size_t)(e4 * 4 + 2) * 256 + tid];
        float w3 = WkT[(size_t)(e4 * 4 + 3) * 256 + tid];
#pragma unroll
        for (int mm = 0; mm < TMQ; ++mm) {
            float4 pv = ((const float4*)ps[mm])[e4];
            acc[mm] += pv.x * w0 + pv.y * w1 + pv.z * w2 + pv.w * w3;
        }
    }
    for (int mm = 0; mm < TMQ; ++mm)
        qk[(size_t)(m0 + mm) * 256 + tid] = acc[mm];
    if (tid < TMQ) {
        float s = 0.f;
        for (int e = 0; e < 256; ++e) s += bk[e] * ps[tid][e];
        qb[m0 + tid] = s;
    }
}

// ---------------- attention: scores -> softmax -> ctx ----------------------
__global__ __launch_bounds__(256) void k_attn(const float* __restrict__ h_grp,
                                              const int* __restrict__ idx,
                                              const int* __restrict__ pos2grp,
                                              const int* __restrict__ msk,
                                              const float* __restrict__ z,
                                              const float* __restrict__ qk,
                                              const float* __restrict__ qb,
                                              float* __restrict__ ctx) {
    int m = blockIdx.x;
    int n = idx[m];
    __shared__ __align__(16) float qks[256];
    __shared__ float attn_s[LL];
    __shared__ int grp_s[LL];
    int tid = threadIdx.x;
    int lane = tid & 63;
    int w = tid >> 6;
    qks[tid] = qk[(size_t)m * 256 + tid];
    if (tid < LL) grp_s[tid] = pos2grp[n * LL + tid];
    __syncthreads();
    float qbv = qb[m];
    const float4* qk4 = (const float4*)qks;
    float4 qv = qk4[lane];
    for (int i = 0; i < 16; ++i) {
        int l = w * 16 + i;
        const float4* h4 = (const float4*)(h_grp + ((size_t)n * LL + l) * DH);
        float4 hv = h4[lane];
        float p = hv.x * qv.x + hv.y * qv.y + hv.z * qv.z + hv.w * qv.w;
        for (int off = 32; off; off >>= 1) p += __shfl_xor(p, off);
        if (lane == 0) {
            float s = (p + qbv) * (1.0f / 16.0f);
            attn_s[l] = msk[n * LL + l] ? s : -INFINITY;
        }
    }
    __syncthreads();
    if (tid < LL) {
        float s = attn_s[tid];
        float mx = s;
        for (int off = 32; off; off >>= 1) mx = fmaxf(mx, __shfl_xor(mx, off));
        float p = __expf(s - mx);
        float sum = p;
        for (int off = 32; off; off >>= 1) sum += __shfl_xor(sum, off);
        attn_s[tid] = p / sum;
    }
    __syncthreads();
    if (tid < DX) {
        int v = tid;
        float acc = 0.f;
        for (int l = 0; l < LL; ++l)
            acc += attn_s[l] * z[(size_t)grp_s[l] * DX + v];
        ctx[(size_t)m * DX + v] = acc;
    }
}

// ---------------- logit = cat(q, ctx) @ Wrel + brel ------------------------
#define TML 4
__global__ __launch_bounds__(256) void k_logit(const float* __restrict__ q,
                                               const float* __restrict__ ctx,
                                               const float* __restrict__ Wrel,
                                               const float* __restrict__ brel,
                                               float* __restrict__ out) {
    __shared__ __align__(16) float ins[TML][640];
    int m0 = blockIdx.x * TML;
    int tid = threadIdx.x;
    for (int j = tid; j < TML * 640; j += 256) {
        int mmj = j / 640, jj = j % 640;
        int mj = m0 + mmj;
        ins[mmj][jj] = (jj < 512) ? q[(size_t)mj * 512 + jj]
                                  : ctx[(size_t)mj * 128 + (jj - 512)];
    }
    __syncthreads();
    int mm = tid >> 6;
    int t = tid & 63;
    float acc = brel[t];
    const float4* in4 = (const float4*)ins[mm];
    for (int j4 = 0; j4 < 160; ++j4) {
        float4 iv = in4[j4];
        acc += iv.x * Wrel[(size_t)(j4 * 4 + 0) * 64 + t];
        acc += iv.y * Wrel[(size_t)(j4 * 4 + 1) * 64 + t];
        acc += iv.z * Wrel[(size_t)(j4 * 4 + 2) * 64 + t];
        acc += iv.w * Wrel[(size_t)(j4 * 4 + 3) * 64 + t];
    }
    out[(size_t)(m0 + mm) * 64 + t] = acc;
}

extern "C" void kernel_launch(void* const* d_in, const int* in_sizes, int n_in,
                              void* d_out, int out_size, void* d_ws, size_t ws_size,
                              hipStream_t stream) {
    const int*   mem     = (const int*)d_in[0];
    const int*   grp     = (const int*)d_in[1];
    const int*   pos2grp = (const int*)d_in[2];
    const float* h_grp   = (const float*)d_in[3];
    const int*   msk     = (const int*)d_in[4];
    const int*   idx     = (const int*)d_in[5];
    const int*   srcv    = (const int*)d_in[6];
    const int*   dstv    = (const int*)d_in[7];
    // d_in[8] = typ (unused by the reference)
    const float* tok_emb = (const float*)d_in[9];
    const float* Wq      = (const float*)d_in[10];
    const float* bq      = (const float*)d_in[11];
    const float* Wk      = (const float*)d_in[12];
    const float* bk      = (const float*)d_in[13];
    const float* Wrel    = (const float*)d_in[14];
    const float* brel    = (const float*)d_in[15];
    float* out = (float*)d_out;

    float* ws = (float*)d_ws;
    size_t off = 0;
    float* z    = ws + off; off += (size_t)GG * DX;       // 524288
    float* q    = ws + off; off += (size_t)MQ * 512;      // 4194304
    float* qp   = ws + off; off += (size_t)MQ * 256;      // 2097152
    float* qk   = ws + off; off += (size_t)MQ * 256;      // 2097152
    float* qb   = ws + off; off += (size_t)MQ;            // 8192
    float* ctx  = ws + off; off += (size_t)MQ * DX;       // 1048576
    float* WkT  = ws + off; off += (size_t)DH * DH;       // 65536
    int* cnt        = (int*)(ws + off); off += GG;        // 4096
    int* ofs        = (int*)(ws + off); off += GG;        // 4096
    int* cur        = (int*)(ws + off); off += GG;        // 4096
    int* tok_sorted = (int*)(ws + off); off += NMEM;      // 262144

    // segment-sum via counting sort (no float atomics)
    hipMemsetAsync(cnt, 0, GG * sizeof(int), stream);
    k_hist<<<NMEM / 256, 256, 0, stream>>>(grp, cnt);
    k_scan<<<1, 1024, 0, stream>>>(cnt, ofs, cur);
    k_permute<<<NMEM / 256, 256, 0, stream>>>(grp, mem, cur, tok_sorted);
    k_zsum<<<GG, 128, 0, stream>>>(ofs, cnt, tok_sorted, tok_emb, z);

    k_qp<<<MQ / TMQ, 256, 0, stream>>>(h_grp, idx, srcv, dstv, Wq, bq, q, qp);

    dim3 tb(32, 32);
    dim3 tg(8, 8);
    k_transpose<<<tg, tb, 0, stream>>>(Wk, WkT);

    k_qk<<<MQ / TMQ, 256, 0, stream>>>(qp, WkT, bk, qk, qb);

    k_attn<<<MQ, 256, 0, stream>>>(h_grp, idx, pos2grp, msk, z, qk, qb, ctx);

    k_logit<<<MQ / TML, 256, 0, stream>>>(q, ctx, Wrel, brel, out);
}